// Round 3
// baseline (1336.368 us; speedup 1.0000x reference)
//
#include <hip/hip_runtime.h>
#include <math.h>

#define NFFT 256
#define NBINS 129
#define HOP 64
#define NFRAMES 65
#define NB 64
#define LX 4096
#define LH 2048
#define LY 1024
#define NCH 64
#define NBR 3
#define NE 8

#define POOLED_BYTES (NB * NBINS * 4)

// ---------------- STFT magnitude + frame-mean pooling ----------------
__global__ __launch_bounds__(192) void stft_kernel(const float* __restrict__ x,
                                                   float* __restrict__ pooled) {
    __shared__ float xw[NFFT];
    __shared__ float ct[NFFT];
    __shared__ float st[NFFT];
    const int f = blockIdx.x, b = blockIdx.y;
    const int tid = threadIdx.x;

    for (int n = tid; n < NFFT; n += 192) {
        float ang = (float)(2.0 * 3.14159265358979323846 / 256.0) * (float)n;
        float s, c;
        sincosf(ang, &s, &c);
        ct[n] = c;
        st[n] = s;
        float win = 0.5f - 0.5f * c;              // Hann, same angle
        int q = f * HOP + n - 128;                // position in x coords
        int xi = q < 0 ? -q : (q >= LX ? (2 * LX - 2 - q) : q);  // reflect
        xw[n] = x[b * LX + xi] * win;
    }
    __syncthreads();

    const int k = tid;
    if (k < NBINS) {
        float re = 0.f, im = 0.f;
        for (int n = 0; n < NFFT; ++n) {
            int idx = (k * n) & 255;
            float v = xw[n];
            re += v * ct[idx];
            im += v * st[idx];
        }
        float mag = sqrtf(re * re + im * im);
        atomicAdd(&pooled[b * NBINS + k], mag);
    }
}

// ---------------- Gating MLP + top-2 softmax ----------------
__global__ __launch_bounds__(256) void gating_kernel(
    const float* __restrict__ pooled,
    const float* __restrict__ Wg1, const float* __restrict__ bg1,
    const float* __restrict__ Wg2, const float* __restrict__ bg2,
    const float* __restrict__ Wg3, const float* __restrict__ bg3,
    int* __restrict__ inds, float* __restrict__ wts) {
    __shared__ float pl[NBINS];
    __shared__ float h1[256];
    __shared__ float h2[128];
    __shared__ float lg[NE];
    const int b = blockIdx.x, tid = threadIdx.x;

    if (tid < NBINS) pl[tid] = pooled[b * NBINS + tid] * (1.0f / (float)NFRAMES);
    __syncthreads();
    {
        float s = bg1[tid];
        for (int k = 0; k < NBINS; ++k) s += pl[k] * Wg1[k * 256 + tid];
        h1[tid] = fmaxf(s, 0.f);
    }
    __syncthreads();
    if (tid < 128) {
        float s = bg2[tid];
        for (int k = 0; k < 256; ++k) s += h1[k] * Wg2[k * 128 + tid];
        h2[tid] = fmaxf(s, 0.f);
    }
    __syncthreads();
    if (tid < NE) {
        float s = bg3[tid];
        for (int k = 0; k < 128; ++k) s += h2[k] * Wg3[k * NE + tid];
        lg[tid] = s;
    }
    __syncthreads();
    if (tid == 0) {
        int i0 = 0;
        float v0 = lg[0];
        for (int i = 1; i < NE; ++i)
            if (lg[i] > v0) { v0 = lg[i]; i0 = i; }
        int i1 = -1;
        float v1 = -3.0e38f;
        for (int i = 0; i < NE; ++i) {
            if (i == i0) continue;
            if (lg[i] > v1) { v1 = lg[i]; i1 = i; }
        }
        float e1 = expf(v1 - v0);
        float w0 = 1.f / (1.f + e1);
        inds[b * 2 + 0] = i0;
        inds[b * 2 + 1] = i1;
        wts[b * 2 + 0] = w0;
        wts[b * 2 + 1] = e1 * w0;
    }
}

// ---------------- Expert two-conv path, top-2 dispatched ----------------
// One launch, grid (u-tiles=8, branch=3, batch=64), 512 threads.
// Branch picks a KSZ-templated body (block-uniform). Per thread: 4 c2 x 4 u.
#define UT 128
#define CCH 16
#define HST 260      // 257 positions padded to float4 rows
#define XSEG 536

template <int KSZ>
__device__ __attribute__((always_inline)) void expert_body(
    const float* __restrict__ x,
    const float* __restrict__ wa, const float* __restrict__ ba,
    const float* __restrict__ wb, const float* __restrict__ bb,
    const int* __restrict__ inds, const float* __restrict__ wts,
    float* __restrict__ out, int br,
    float* xl, float* hl, float* wbl4) {
    const int u0 = blockIdx.x * UT;
    const int b = blockIdx.z;
    const int tid = threadIdx.x;
    const int pad = KSZ >> 1;

    const int t0 = 2 * u0 - 1;          // first h position needed
    const int x0 = 2 * t0 - pad;        // first x index needed
    const int xcnt = 513 + KSZ;

    for (int j = tid; j < xcnt; j += 512) {
        int xi = x0 + j;
        xl[j] = (xi >= 0 && xi < LX) ? x[b * LX + xi] : 0.f;   // conv zero-pad
    }

    const int l5 = tid & 31;    // u-lane: 4 consecutive u per thread
    const int cg = tid >> 5;    // c2 group 0..15; c2 = cg + 16*j

    const int ub = u0 + 4 * l5;     // thread's first u
    const int pb = 8 * l5;          // thread's first h position (local)

    float fin[4][4];
#pragma unroll
    for (int j = 0; j < 4; ++j)
#pragma unroll
        for (int m = 0; m < 4; ++m) fin[j][m] = 0.f;

    for (int slot = 0; slot < 2; ++slot) {
        const int e = inds[b * 2 + slot];
        const float wj = wts[b * 2 + slot];

        float acc[4][4];
#pragma unroll
        for (int j = 0; j < 4; ++j) {
            float bbv = bb[e * NCH + cg + 16 * j];
#pragma unroll
            for (int m = 0; m < 4; ++m) acc[j][m] = bbv;
        }

        for (int c0 = 0; c0 < NCH; c0 += CCH) {
            __syncthreads();   // protect LDS from previous chunk's readers

            // phase A: first conv + relu into LDS, 4 positions per group.
            for (int idx = tid; idx < CCH * 65; idx += 512) {
                int cl = idx / 65, g = idx - cl * 65;
                int pbase = 4 * g;
                const float* wrow = wa + (e * NCH + c0 + cl) * KSZ;
                float wr[KSZ];
#pragma unroll
                for (int i = 0; i < KSZ; ++i) wr[i] = wrow[i];
                float bv = ba[e * NCH + c0 + cl];
                float4 xv0 = *(const float4*)&xl[8 * g + 0];
                float4 xv1 = *(const float4*)&xl[8 * g + 4];
                float4 xv2 = *(const float4*)&xl[8 * g + 8];
                float4 xv3 = *(const float4*)&xl[8 * g + 12];
                float xv[16] = {xv0.x, xv0.y, xv0.z, xv0.w,
                                xv1.x, xv1.y, xv1.z, xv1.w,
                                xv2.x, xv2.y, xv2.z, xv2.w,
                                xv3.x, xv3.y, xv3.z, xv3.w};
                float4 hv;
                float hm[4];
#pragma unroll
                for (int m = 0; m < 4; ++m) {
                    float s = bv;
#pragma unroll
                    for (int i = 0; i < KSZ; ++i)
                        s += wr[i] * xv[2 * m + i];
                    int t = t0 + pbase + m;
                    hm[m] = (t >= 0 && t < LH) ? fmaxf(s, 0.f) : 0.f;
                }
                hv.x = hm[0]; hv.y = hm[1]; hv.z = hm[2]; hv.w = hm[3];
                *(float4*)&hl[cl * HST + pbase] = hv;
            }

            // stage second-conv weights padded to 4: wbl4[c2*64 + cl*4 + i]
            for (int idx = tid; idx < NCH * CCH * 3; idx += 512) {
                int c2 = idx / 48, r = idx - c2 * 48;
                int cl = r / 3, i = r - cl * 3;
                wbl4[c2 * 64 + cl * 4 + i] =
                    wb[(e * NCH + c2) * (NCH * 3) + c0 * 3 + r];
            }
            __syncthreads();

            // phase C: second conv, 4 c2 x 4 u per thread, b128 LDS reads
#pragma unroll
            for (int cl = 0; cl < CCH; ++cl) {
                float4 ha = *(const float4*)&hl[cl * HST + pb];
                float4 hb = *(const float4*)&hl[cl * HST + pb + 4];
                float hc = hl[cl * HST + pb + 8];
#pragma unroll
                for (int j = 0; j < 4; ++j) {
                    int c2 = cg + 16 * j;
                    float4 w = *(const float4*)&wbl4[c2 * 64 + cl * 4];
                    acc[j][0] += w.x * ha.x + w.y * ha.y + w.z * ha.z;
                    acc[j][1] += w.x * ha.z + w.y * ha.w + w.z * hb.x;
                    acc[j][2] += w.x * hb.x + w.y * hb.y + w.z * hb.z;
                    acc[j][3] += w.x * hb.z + w.y * hb.w + w.z * hc;
                }
            }
        }

#pragma unroll
        for (int j = 0; j < 4; ++j)
#pragma unroll
            for (int m = 0; m < 4; ++m)
                fin[j][m] += wj * fmaxf(acc[j][m], 0.f);
    }

#pragma unroll
    for (int j = 0; j < 4; ++j) {
        int c2 = cg + 16 * j;
        long row = (long)(b * 192 + br * 64 + c2) * LY;
        float4 o;
        o.x = fin[j][0]; o.y = fin[j][1]; o.z = fin[j][2]; o.w = fin[j][3];
        *(float4*)&out[row + ub] = o;
    }
}

__global__ __launch_bounds__(512, 4) void expert_kernel(
    const float* __restrict__ x,
    const float* __restrict__ wa3, const float* __restrict__ ba3,
    const float* __restrict__ wb3, const float* __restrict__ bb3,
    const float* __restrict__ wa5, const float* __restrict__ ba5,
    const float* __restrict__ wb5, const float* __restrict__ bb5,
    const float* __restrict__ wa7, const float* __restrict__ ba7,
    const float* __restrict__ wb7, const float* __restrict__ bb7,
    const int* __restrict__ inds, const float* __restrict__ wts,
    float* __restrict__ out) {
    __shared__ float xl[XSEG];
    __shared__ float hl[CCH * HST];        // 16.6 KB
    __shared__ float wbl4[NCH * CCH * 4];  // 16 KB

    const int br = blockIdx.y;
    if (br == 0)
        expert_body<3>(x, wa3, ba3, wb3, bb3, inds, wts, out, 0, xl, hl, wbl4);
    else if (br == 1)
        expert_body<5>(x, wa5, ba5, wb5, bb5, inds, wts, out, 1, xl, hl, wbl4);
    else
        expert_body<7>(x, wa7, ba7, wb7, bb7, inds, wts, out, 2, xl, hl, wbl4);
}

extern "C" void kernel_launch(void* const* d_in, const int* in_sizes, int n_in,
                              void* d_out, int out_size, void* d_ws, size_t ws_size,
                              hipStream_t stream) {
    const float* x   = (const float*)d_in[0];
    const float* Wg1 = (const float*)d_in[1];
    const float* bg1 = (const float*)d_in[2];
    const float* Wg2 = (const float*)d_in[3];
    const float* bg2 = (const float*)d_in[4];
    const float* Wg3 = (const float*)d_in[5];
    const float* bg3 = (const float*)d_in[6];
    const float* wa3 = (const float*)d_in[7];
    const float* ba3 = (const float*)d_in[8];
    const float* wb3 = (const float*)d_in[9];
    const float* bb3 = (const float*)d_in[10];
    const float* wa5 = (const float*)d_in[11];
    const float* ba5 = (const float*)d_in[12];
    const float* wb5 = (const float*)d_in[13];
    const float* bb5 = (const float*)d_in[14];
    const float* wa7 = (const float*)d_in[15];
    const float* ba7 = (const float*)d_in[16];
    const float* wb7 = (const float*)d_in[17];
    const float* bb7 = (const float*)d_in[18];

    float* pooled = (float*)d_ws;
    int* inds = (int*)((char*)d_ws + POOLED_BYTES);
    float* wts = (float*)((char*)d_ws + POOLED_BYTES + 512);

    hipMemsetAsync(d_ws, 0, POOLED_BYTES, stream);
    stft_kernel<<<dim3(NFRAMES, NB), 192, 0, stream>>>(x, pooled);
    gating_kernel<<<NB, 256, 0, stream>>>(pooled, Wg1, bg1, Wg2, bg2, Wg3, bg3,
                                          inds, wts);
    expert_kernel<<<dim3(LY / UT, NBR, NB), 512, 0, stream>>>(
        x, wa3, ba3, wb3, bb3, wa5, ba5, wb5, bb5, wa7, ba7, wb7, bb7,
        inds, wts, (float*)d_out);
}

// Round 5
// 525.806 us; speedup vs baseline: 2.5416x; 2.5416x over previous
//
#include <hip/hip_runtime.h>
#include <math.h>

#define NFFT 256
#define NBINS 129
#define HOP 64
#define NFRAMES 65
#define NB 64
#define LX 4096
#define LH 2048
#define LY 1024
#define NCH 64
#define NBR 3
#define NE 8

#define POOLED_BYTES (NB * NBINS * 4)

// ---------------- STFT magnitude + frame-mean pooling ----------------
__global__ __launch_bounds__(192) void stft_kernel(const float* __restrict__ x,
                                                   float* __restrict__ pooled) {
    __shared__ float xw[NFFT];
    __shared__ float ct[NFFT];
    __shared__ float st[NFFT];
    const int f = blockIdx.x, b = blockIdx.y;
    const int tid = threadIdx.x;

    for (int n = tid; n < NFFT; n += 192) {
        float ang = (float)(2.0 * 3.14159265358979323846 / 256.0) * (float)n;
        float s, c;
        sincosf(ang, &s, &c);
        ct[n] = c;
        st[n] = s;
        float win = 0.5f - 0.5f * c;              // Hann, same angle
        int q = f * HOP + n - 128;                // position in x coords
        int xi = q < 0 ? -q : (q >= LX ? (2 * LX - 2 - q) : q);  // reflect
        xw[n] = x[b * LX + xi] * win;
    }
    __syncthreads();

    const int k = tid;
    if (k < NBINS) {
        float re = 0.f, im = 0.f;
        for (int n = 0; n < NFFT; ++n) {
            int idx = (k * n) & 255;
            float v = xw[n];
            re += v * ct[idx];
            im += v * st[idx];
        }
        float mag = sqrtf(re * re + im * im);
        atomicAdd(&pooled[b * NBINS + k], mag);
    }
}

// ---------------- Gating MLP + top-2 softmax ----------------
__global__ __launch_bounds__(256) void gating_kernel(
    const float* __restrict__ pooled,
    const float* __restrict__ Wg1, const float* __restrict__ bg1,
    const float* __restrict__ Wg2, const float* __restrict__ bg2,
    const float* __restrict__ Wg3, const float* __restrict__ bg3,
    int* __restrict__ inds, float* __restrict__ wts) {
    __shared__ float pl[NBINS];
    __shared__ float h1[256];
    __shared__ float h2[128];
    __shared__ float lg[NE];
    const int b = blockIdx.x, tid = threadIdx.x;

    if (tid < NBINS) pl[tid] = pooled[b * NBINS + tid] * (1.0f / (float)NFRAMES);
    __syncthreads();
    {
        float s = bg1[tid];
        for (int k = 0; k < NBINS; ++k) s += pl[k] * Wg1[k * 256 + tid];
        h1[tid] = fmaxf(s, 0.f);
    }
    __syncthreads();
    if (tid < 128) {
        float s = bg2[tid];
        for (int k = 0; k < 256; ++k) s += h1[k] * Wg2[k * 128 + tid];
        h2[tid] = fmaxf(s, 0.f);
    }
    __syncthreads();
    if (tid < NE) {
        float s = bg3[tid];
        for (int k = 0; k < 128; ++k) s += h2[k] * Wg3[k * NE + tid];
        lg[tid] = s;
    }
    __syncthreads();
    if (tid == 0) {
        int i0 = 0;
        float v0 = lg[0];
        for (int i = 1; i < NE; ++i)
            if (lg[i] > v0) { v0 = lg[i]; i0 = i; }
        int i1 = -1;
        float v1 = -3.0e38f;
        for (int i = 0; i < NE; ++i) {
            if (i == i0) continue;
            if (lg[i] > v1) { v1 = lg[i]; i1 = i; }
        }
        float e1 = expf(v1 - v0);
        float w0 = 1.f / (1.f + e1);
        inds[b * 2 + 0] = i0;
        inds[b * 2 + 1] = i1;
        wts[b * 2 + 0] = w0;
        wts[b * 2 + 1] = e1 * w0;
    }
}

// ---------------- Expert two-conv path, top-2 dispatched ----------------
// One launch, grid (u-tiles=8, branch=3, batch=64), 512 threads.
// Branch picks a KSZ-templated body (block-uniform). Per thread: 4 c2 x 4 u.
// hl bank swizzle (BIJECTIVE, xor within octet): float4 group G is stored at
// word 4*(G ^ ((G>>1)&7)). b0'=b0^b1, b1'=b1^b2, b2'=b2^b3, upper bits kept
// -> invertible, stays in [G&~7, G|7]. Phase-C stride-8 reads spread across
// all 8 bank-quads per 8 lanes (4-way floor instead of 8-way).
#define UT 128
#define CCH 16
#define HST 260      // max stored word 4*64+3 = 259
#define XSEG 536

__device__ __forceinline__ int swzg(int G) { return G ^ ((G >> 1) & 7); }

template <int KSZ>
__device__ __attribute__((always_inline)) void expert_body(
    const float* __restrict__ x,
    const float* __restrict__ wa, const float* __restrict__ ba,
    const float* __restrict__ wb, const float* __restrict__ bb,
    const int* __restrict__ inds, const float* __restrict__ wts,
    float* __restrict__ out, int br,
    float* xl, float* hl, float* wbl4) {
    const int u0 = blockIdx.x * UT;
    const int b = blockIdx.z;
    const int tid = threadIdx.x;
    const int pad = KSZ >> 1;

    const int t0 = 2 * u0 - 1;          // first h position needed
    const int x0 = 2 * t0 - pad;        // first x index needed
    const int xcnt = 513 + KSZ;

    for (int j = tid; j < xcnt; j += 512) {
        int xi = x0 + j;
        xl[j] = (xi >= 0 && xi < LX) ? x[b * LX + xi] : 0.f;   // conv zero-pad
    }

    const int l5 = tid & 31;    // u-lane: 4 consecutive u per thread
    const int cg = tid >> 5;    // c2 group 0..15; c2 = cg + 16*j

    const int ub = u0 + 4 * l5;     // thread's first u
    // thread needs h positions 8*l5 .. 8*l5+8 = groups 2*l5, 2*l5+1, 2*l5+2
    const int swa = 4 * swzg(2 * l5);        // float4: positions 8l5..+3
    const int swb = 4 * swzg(2 * l5 + 1);    // float4: positions 8l5+4..+7
    const int swc = 4 * swzg(2 * l5 + 2);    // scalar: position 8l5+8

    float fin[4][4];
#pragma unroll
    for (int j = 0; j < 4; ++j)
#pragma unroll
        for (int m = 0; m < 4; ++m) fin[j][m] = 0.f;

    for (int slot = 0; slot < 2; ++slot) {
        const int e = inds[b * 2 + slot];
        const float wj = wts[b * 2 + slot];

        float acc[4][4];
#pragma unroll
        for (int j = 0; j < 4; ++j) {
            float bbv = bb[e * NCH + cg + 16 * j];
#pragma unroll
            for (int m = 0; m < 4; ++m) acc[j][m] = bbv;
        }

        for (int c0 = 0; c0 < NCH; c0 += CCH) {
            __syncthreads();   // protect LDS from previous chunk's readers

            // phase A: first conv + relu into LDS, 4 positions per group.
            for (int idx = tid; idx < CCH * 65; idx += 512) {
                int cl = idx / 65, g = idx - cl * 65;
                int pbase = 4 * g;
                const float* wrow = wa + (e * NCH + c0 + cl) * KSZ;
                float wr[KSZ];
#pragma unroll
                for (int i = 0; i < KSZ; ++i) wr[i] = wrow[i];
                float bv = ba[e * NCH + c0 + cl];
                float4 xv0 = *(const float4*)&xl[8 * g + 0];
                float4 xv1 = *(const float4*)&xl[8 * g + 4];
                float4 xv2 = *(const float4*)&xl[8 * g + 8];
                float4 xv3 = *(const float4*)&xl[8 * g + 12];
                float xv[16] = {xv0.x, xv0.y, xv0.z, xv0.w,
                                xv1.x, xv1.y, xv1.z, xv1.w,
                                xv2.x, xv2.y, xv2.z, xv2.w,
                                xv3.x, xv3.y, xv3.z, xv3.w};
                float4 hv;
                float hm[4];
#pragma unroll
                for (int m = 0; m < 4; ++m) {
                    float s = bv;
#pragma unroll
                    for (int i = 0; i < KSZ; ++i)
                        s += wr[i] * xv[2 * m + i];
                    int t = t0 + pbase + m;
                    hm[m] = (t >= 0 && t < LH) ? fmaxf(s, 0.f) : 0.f;
                }
                hv.x = hm[0]; hv.y = hm[1]; hv.z = hm[2]; hv.w = hm[3];
                *(float4*)&hl[cl * HST + 4 * swzg(g)] = hv;
            }

            // stage second-conv weights padded to 4: wbl4[c2*64 + cl*4 + i]
            for (int idx = tid; idx < NCH * CCH * 3; idx += 512) {
                int c2 = idx / 48, r = idx - c2 * 48;
                int cl = r / 3, i = r - cl * 3;
                wbl4[c2 * 64 + cl * 4 + i] =
                    wb[(e * NCH + c2) * (NCH * 3) + c0 * 3 + r];
            }
            __syncthreads();

            // phase C: second conv, 4 c2 x 4 u per thread, b128 LDS reads
#pragma unroll
            for (int cl = 0; cl < CCH; ++cl) {
                float4 ha = *(const float4*)&hl[cl * HST + swa];
                float4 hb = *(const float4*)&hl[cl * HST + swb];
                float hc = hl[cl * HST + swc];
#pragma unroll
                for (int j = 0; j < 4; ++j) {
                    int c2 = cg + 16 * j;
                    float4 w = *(const float4*)&wbl4[c2 * 64 + cl * 4];
                    acc[j][0] += w.x * ha.x + w.y * ha.y + w.z * ha.z;
                    acc[j][1] += w.x * ha.z + w.y * ha.w + w.z * hb.x;
                    acc[j][2] += w.x * hb.x + w.y * hb.y + w.z * hb.z;
                    acc[j][3] += w.x * hb.z + w.y * hb.w + w.z * hc;
                }
            }
        }

#pragma unroll
        for (int j = 0; j < 4; ++j)
#pragma unroll
            for (int m = 0; m < 4; ++m)
                fin[j][m] += wj * fmaxf(acc[j][m], 0.f);
    }

#pragma unroll
    for (int j = 0; j < 4; ++j) {
        int c2 = cg + 16 * j;
        long row = (long)(b * 192 + br * 64 + c2) * LY;
        float4 o;
        o.x = fin[j][0]; o.y = fin[j][1]; o.z = fin[j][2]; o.w = fin[j][3];
        *(float4*)&out[row + ub] = o;
    }
}

__global__ __launch_bounds__(512, 2) void expert_kernel(
    const float* __restrict__ x,
    const float* __restrict__ wa3, const float* __restrict__ ba3,
    const float* __restrict__ wb3, const float* __restrict__ bb3,
    const float* __restrict__ wa5, const float* __restrict__ ba5,
    const float* __restrict__ wb5, const float* __restrict__ bb5,
    const float* __restrict__ wa7, const float* __restrict__ ba7,
    const float* __restrict__ wb7, const float* __restrict__ bb7,
    const int* __restrict__ inds, const float* __restrict__ wts,
    float* __restrict__ out) {
    __shared__ float xl[XSEG];
    __shared__ float hl[CCH * HST];        // 16.6 KB
    __shared__ float wbl4[NCH * CCH * 4];  // 16 KB

    const int br = blockIdx.y;
    if (br == 0)
        expert_body<3>(x, wa3, ba3, wb3, bb3, inds, wts, out, 0, xl, hl, wbl4);
    else if (br == 1)
        expert_body<5>(x, wa5, ba5, wb5, bb5, inds, wts, out, 1, xl, hl, wbl4);
    else
        expert_body<7>(x, wa7, ba7, wb7, bb7, inds, wts, out, 2, xl, hl, wbl4);
}

extern "C" void kernel_launch(void* const* d_in, const int* in_sizes, int n_in,
                              void* d_out, int out_size, void* d_ws, size_t ws_size,
                              hipStream_t stream) {
    const float* x   = (const float*)d_in[0];
    const float* Wg1 = (const float*)d_in[1];
    const float* bg1 = (const float*)d_in[2];
    const float* Wg2 = (const float*)d_in[3];
    const float* bg2 = (const float*)d_in[4];
    const float* Wg3 = (const float*)d_in[5];
    const float* bg3 = (const float*)d_in[6];
    const float* wa3 = (const float*)d_in[7];
    const float* ba3 = (const float*)d_in[8];
    const float* wb3 = (const float*)d_in[9];
    const float* bb3 = (const float*)d_in[10];
    const float* wa5 = (const float*)d_in[11];
    const float* ba5 = (const float*)d_in[12];
    const float* wb5 = (const float*)d_in[13];
    const float* bb5 = (const float*)d_in[14];
    const float* wa7 = (const float*)d_in[15];
    const float* ba7 = (const float*)d_in[16];
    const float* wb7 = (const float*)d_in[17];
    const float* bb7 = (const float*)d_in[18];

    float* pooled = (float*)d_ws;
    int* inds = (int*)((char*)d_ws + POOLED_BYTES);
    float* wts = (float*)((char*)d_ws + POOLED_BYTES + 512);

    hipMemsetAsync(d_ws, 0, POOLED_BYTES, stream);
    stft_kernel<<<dim3(NFRAMES, NB), 192, 0, stream>>>(x, pooled);
    gating_kernel<<<NB, 256, 0, stream>>>(pooled, Wg1, bg1, Wg2, bg2, Wg3, bg3,
                                          inds, wts);
    expert_kernel<<<dim3(LY / UT, NBR, NB), 512, 0, stream>>>(
        x, wa3, ba3, wb3, bb3, wa5, ba5, wb5, bb5, wa7, ba7, wb7, bb7,
        inds, wts, (float*)d_out);
}